// Round 9
// baseline (267.286 us; speedup 1.0000x reference)
//
#include <hip/hip_runtime.h>
#include <hip/hip_fp16.h>
#include <stdint.h>

typedef unsigned long long u64;
typedef _Float16 half8 __attribute__((ext_vector_type(8)));
typedef float f32x4 __attribute__((ext_vector_type(4)));

#define EPB 6144      // edges staged per k_bin block
#define CAPC 5440     // bucket capacity (mean 4096 + huge margin)

__device__ __forceinline__ float sigm(float x) { return 1.0f / (1.0f + __expf(-x)); }
__device__ __forceinline__ float tanhfast(float x) { return 1.0f - 2.0f / (__expf(2.0f * x) + 1.0f); }
__device__ __forceinline__ int rli(int v, int k) { return __builtin_amdgcn_readlane(v, k); }
__device__ __forceinline__ float rlf(float v, int k) {
    return __int_as_float(__builtin_amdgcn_readlane(__float_as_int(v), k));
}

// Fragment-packed fp16 weight build + bias combine + cursor zero. Grid 113x256.
__global__ void k_pre(const float* __restrict__ Wcz, const float* __restrict__ bcz,
                      const float* __restrict__ Wcr, const float* __restrict__ bcr,
                      const float* __restrict__ Wch, const float* __restrict__ bch,
                      const float* __restrict__ Wlz, const float* __restrict__ blz,
                      const float* __restrict__ Wlr, const float* __restrict__ blr,
                      const float* __restrict__ Wlh, const float* __restrict__ blh,
                      __half* __restrict__ B1f, __half* __restrict__ B2f,
                      float* __restrict__ bias, int* __restrict__ cursor) {
    int tid = blockIdx.x * 256 + threadIdx.x;
    if (tid < 1024) cursor[tid] = 0;
    if (tid < 24576) {
        int k = tid / 192, nc = tid % 192;
        int g = nc >> 6, j = nc & 63;
        const float* Wc = (g == 0) ? Wcz : (g == 1) ? Wcr : Wch;
        const float* Wl = (g == 0) ? Wlz : (g == 1) ? Wlr : Wlh;
        float v;
        if (k < 64) {
            float acc = 0.f;
            for (int m = 0; m < 64; m++) acc += Wc[k * 64 + m] * Wl[m * 64 + j];
            v = acc;
        } else {
            v = (g < 2) ? Wl[k * 64 + j] : 0.f;
        }
        int kt = k >> 5, nt = nc >> 4;
        int lane = (((k >> 3) & 3) << 4) | (nc & 15);
        B1f[(((kt * 12 + nt) * 64 + lane) << 3) + (k & 7)] = (__half)v;
    } else if (tid < 24576 + 4096) {
        int t = tid - 24576;
        int k = t >> 6, nc = t & 63;
        float v = Wlh[(64 + k) * 64 + nc];
        int kt = k >> 5, nt = nc >> 4;
        int lane = (((k >> 3) & 3) << 4) | (nc & 15);
        B2f[(((kt * 4 + nt) * 64 + lane) << 3) + (k & 7)] = (__half)v;
    } else if (tid < 24576 + 4096 + 192) {
        int t = tid - 24576 - 4096;
        int g = t >> 6, j = t & 63;
        const float* bc = (g == 0) ? bcz : (g == 1) ? bcr : bch;
        const float* Wl = (g == 0) ? Wlz : (g == 1) ? Wlr : Wlh;
        const float* bl = (g == 0) ? blz : (g == 1) ? blr : blh;
        float acc = bl[j];
        for (int m = 0; m < 64; m++) acc += bc[m] * Wl[m * 64 + j];
        bias[t] = acc;
    }
}

// One-pass LDS-staged counting sort of edges into 256-node dst-buckets.
// rec u64: [63:32]=ew bits, [24:17]=dst&255, [16:0]=src
__global__ void __launch_bounds__(1024) k_bin(const int* __restrict__ src, const int* __restrict__ dst,
                                              const float* __restrict__ ew,
                                              int* __restrict__ cursor, u64* __restrict__ binned,
                                              int E, int R) {
    __shared__ u64 recs[EPB];        // 48 KB
    __shared__ int hist[512];
    __shared__ int loff[512];
    __shared__ int curL[512];
    __shared__ int gbase[512];

    int tid = threadIdx.x;
    if (tid < 512) hist[tid] = 0;
    __syncthreads();

    int base = blockIdx.x * EPB;
    int cntE = min(EPB, E - base);

    u64 myrec[6];
    int myr[6];
#pragma unroll
    for (int j = 0; j < 6; j++) {
        int idx = tid + j * 1024;
        if (idx < cntE) {
            int e = base + idx;
            int d = dst[e], s = src[e];
            float w = ew[e];
            int r = d >> 8;
            myr[j] = r;
            myrec[j] = (u64)((unsigned)s | ((unsigned)(d & 255) << 17)) | ((u64)__float_as_uint(w) << 32);
            atomicAdd(&hist[r], 1);
        } else myr[j] = -1;
    }
    __syncthreads();

    // wave 0: exclusive scan of hist[512] -> loff
    if (tid < 64) {
        int sums[8], tot = 0;
#pragma unroll
        for (int q = 0; q < 8; q++) { sums[q] = hist[tid * 8 + q]; tot += sums[q]; }
        int scan = tot;
#pragma unroll
        for (int o = 1; o < 64; o <<= 1) {
            int v = __shfl_up(scan, o);
            if (tid >= o) scan += v;
        }
        int run = scan - tot;   // exclusive
#pragma unroll
        for (int q = 0; q < 8; q++) { loff[tid * 8 + q] = run; run += sums[q]; }
    }
    if (tid < 512) curL[tid] = 0;
    if (tid < R) {
        int hcnt = hist[tid];
        if (hcnt > 0) gbase[tid] = tid * CAPC + atomicAdd(&cursor[tid], hcnt);
    }
    __syncthreads();

    // place into LDS, bucket-sorted
#pragma unroll
    for (int j = 0; j < 6; j++) {
        if (myr[j] >= 0) {
            int p = atomicAdd(&curL[myr[j]], 1);
            recs[loff[myr[j]] + p] = myrec[j];
        }
    }
    __syncthreads();

    // flush: wave w handles buckets w, w+16, ... with coalesced runs
    int wave = tid >> 6, lane = tid & 63;
    for (int r = wave; r < R; r += 16) {
        int len = hist[r];
        if (!len) continue;
        int gb = gbase[r], lo = loff[r];
        int capEnd = (r + 1) * CAPC;
        for (int i = lane; i < len; i += 64)
            if (gb + i < capEnd) binned[(size_t)(gb + i)] = recs[lo + i];
    }
}

// Per-bucket: histogram+degree -> scan -> dinv/off/len; ticket-sort to CSR in place;
// also builds xs[i] = dinv[i] * x[i] in fp16 for this bucket's 256 nodes.
__global__ void __launch_bounds__(1024) k_sort(const int* __restrict__ cursor,
                                               u64* __restrict__ binned,
                                               const float2* __restrict__ x2,
                                               float* __restrict__ dinv,
                                               __half2* __restrict__ xs2,
                                               int* __restrict__ off_g, int* __restrict__ len_g,
                                               int n) {
    __shared__ u64 srt[CAPC];        // 43.5 KB
    __shared__ int hist[256];
    __shared__ int noff[256];
    __shared__ int cur[256];
    __shared__ float degw[256];

    int r = blockIdx.x, tid = threadIdx.x;
    if (tid < 256) { hist[tid] = 0; degw[tid] = 0.f; }
    __syncthreads();

    int cnt = min(cursor[r], CAPC);
    u64* B = binned + (size_t)r * CAPC;

    // pass A: histogram + weighted degree
    for (int i = tid; i < cnt; i += 1024) {
        u64 m = B[i];
        int dl = ((unsigned)m >> 17) & 255;
        atomicAdd(&hist[dl], 1);
        atomicAdd(&degw[dl], __uint_as_float((unsigned)(m >> 32)));
    }
    __syncthreads();

    // wave 0: exclusive scan hist[256] -> noff
    if (tid < 64) {
        int s0 = hist[tid * 4], s1 = hist[tid * 4 + 1], s2 = hist[tid * 4 + 2], s3 = hist[tid * 4 + 3];
        int tot = s0 + s1 + s2 + s3;
        int scan = tot;
#pragma unroll
        for (int o = 1; o < 64; o <<= 1) {
            int v = __shfl_up(scan, o);
            if (tid >= o) scan += v;
        }
        int run = scan - tot;
        noff[tid * 4] = run; run += s0;
        noff[tid * 4 + 1] = run; run += s1;
        noff[tid * 4 + 2] = run; run += s2;
        noff[tid * 4 + 3] = run;
    }
    __syncthreads();

    if (tid < 256) {
        int node = r * 256 + tid;
        float dv = rsqrtf(1.0f + degw[tid]);
        if (node < n) {
            dinv[node] = dv;
            off_g[node] = r * CAPC + noff[tid];
            len_g[node] = hist[tid];
        }
        cur[tid] = noff[tid];
        degw[tid] = dv;          // degw now holds dinv for the xs build
    }
    __syncthreads();

    // pass B: ticket-place into sorted LDS order (global L2-hot re-read -> LDS)
    for (int i = tid; i < cnt; i += 1024) {
        u64 m = B[i];
        int dl = ((unsigned)m >> 17) & 255;
        int p = atomicAdd(&cur[dl], 1);
        srt[p] = (u64)((unsigned)m & 0x1FFFF) | (m & 0xFFFFFFFF00000000ULL);
    }
    __syncthreads();

    // coalesced in-place flush + xs build (independent streams)
    for (int i = tid; i < cnt; i += 1024) B[i] = srt[i];
    int nbase = r * 256;
    for (int i = tid; i < 256 * 32; i += 1024) {
        int nl = i >> 5, cp = i & 31;
        int node = nbase + nl;
        if (node < n) {
            float2 xv = x2[((size_t)node << 5) + cp];
            float dv = degw[nl];
            xs2[((size_t)node << 5) + cp] = __floats2half2_rn(dv * xv.x, dv * xv.y);
        }
    }
}

// Fused gather + gates + head. Wave-autonomous: each wave owns a 16-node m-tile.
// No __syncthreads; LDS strip per wave for agg/hr transpose; B-frags from global (L2).
__global__ void __launch_bounds__(256, 2) k_gnode(
        const int* __restrict__ off_g, const int* __restrict__ len_g,
        const u64* __restrict__ csr, const float* __restrict__ dinv,
        const __half* __restrict__ xs, const float* __restrict__ hglob,
        const __half* __restrict__ B1f_g, const __half* __restrict__ B2f_g,
        const float* __restrict__ bias_g, const float* __restrict__ Whead,
        const float* __restrict__ bhead,
        float* __restrict__ out_head, float* __restrict__ out_h, int n) {

    __shared__ __half buf[4][16 * 72];   // per-wave transpose strip (stride 72: no conflicts)

    int tid = threadIdx.x;
    int lane = tid & 63;
    int wave = __builtin_amdgcn_readfirstlane(tid >> 6);
    int quad = lane >> 4;
    int l15 = lane & 15;

    int mb = blockIdx.x * 64 + wave * 16;   // n % 16 == 0: m-tiles all-or-nothing
    if (mb >= n) return;
    __half* myb = &buf[wave][0];

    // ---- phase 1: gather agg for this wave's 16 nodes -> LDS rows [m][c] ----
    for (int t = 0; t < 16; t++) {
        int d = mb + t;
        int o0 = off_g[d], L = len_g[d];
        float dd = dinv[d];
        float acc[16];
#pragma unroll
        for (int j = 0; j < 16; j++) acc[j] = 0.f;
        acc[0] = (float)xs[((size_t)d << 6) + lane];   // self term (scaled space)
        for (int base = 0; base < L; base += 64) {
            int c = min(64, L - base);
            u64 m = (lane < c) ? csr[(size_t)(o0 + base) + lane] : 0;
            int s_l = (unsigned)m & 0x1FFFF;
            float w_l = __uint_as_float((unsigned)(m >> 32));
            int k = 0;
            for (; k + 16 <= c; k += 16) {
                int ss[16]; float ww[16], xr[16];
#pragma unroll
                for (int j = 0; j < 16; j++) { ss[j] = rli(s_l, k + j); ww[j] = rlf(w_l, k + j); }
#pragma unroll
                for (int j = 0; j < 16; j++) xr[j] = (float)xs[((size_t)ss[j] << 6) + lane];
#pragma unroll
                for (int j = 0; j < 16; j++) acc[j] = fmaf(ww[j], xr[j], acc[j]);
            }
            for (; k + 4 <= c; k += 4) {
                int ss[4]; float ww[4], xr[4];
#pragma unroll
                for (int j = 0; j < 4; j++) { ss[j] = rli(s_l, k + j); ww[j] = rlf(w_l, k + j); }
#pragma unroll
                for (int j = 0; j < 4; j++) xr[j] = (float)xs[((size_t)ss[j] << 6) + lane];
#pragma unroll
                for (int j = 0; j < 4; j++) acc[j] = fmaf(ww[j], xr[j], acc[j]);
            }
            for (; k < c; k++) {
                int s0 = rli(s_l, k);
                float w0 = rlf(w_l, k);
                acc[0] = fmaf(w0, (float)xs[((size_t)s0 << 6) + lane], acc[0]);
            }
        }
        float s = ((acc[0] + acc[1]) + (acc[2] + acc[3])) + ((acc[4] + acc[5]) + (acc[6] + acc[7]))
                + ((acc[8] + acc[9]) + (acc[10] + acc[11])) + ((acc[12] + acc[13]) + (acc[14] + acc[15]));
        myb[t * 72 + lane] = (__half)(dd * s);
    }
    __builtin_amdgcn_s_waitcnt(0);   // drain DS writes before cross-lane read (same wave)

    // ---- phase 2: A fragments. k-tiles 0,1 = agg (LDS); 2,3 = h (global f32 -> fp16) ----
    half8 a0 = *(const half8*)(myb + l15 * 72 + quad * 8);
    half8 a1 = *(const half8*)(myb + l15 * 72 + 32 + quad * 8);
    const float* hrow = hglob + (size_t)(mb + l15) * 64 + quad * 8;
    half8 a2, a3;
#pragma unroll
    for (int j = 0; j < 8; j++) a2[j] = (_Float16)hrow[j];
#pragma unroll
    for (int j = 0; j < 8; j++) a3[j] = (_Float16)hrow[32 + j];

    // ---- phase 3: GEMM1 [16 x 128] @ B1[128 x 192], B from global (L2-broadcast) ----
    const half8* B1v = (const half8*)B1f_g;
    const half8* B2v = (const half8*)B2f_g;
    f32x4 acc12[12];
#pragma unroll
    for (int nt = 0; nt < 12; nt++) acc12[nt] = (f32x4){0.f, 0.f, 0.f, 0.f};
#pragma unroll
    for (int nt = 0; nt < 12; nt++) {
        acc12[nt] = __builtin_amdgcn_mfma_f32_16x16x32_f16(a0, B1v[(0 * 12 + nt) * 64 + lane], acc12[nt], 0, 0, 0);
        acc12[nt] = __builtin_amdgcn_mfma_f32_16x16x32_f16(a1, B1v[(1 * 12 + nt) * 64 + lane], acc12[nt], 0, 0, 0);
        acc12[nt] = __builtin_amdgcn_mfma_f32_16x16x32_f16(a2, B1v[(2 * 12 + nt) * 64 + lane], acc12[nt], 0, 0, 0);
        acc12[nt] = __builtin_amdgcn_mfma_f32_16x16x32_f16(a3, B1v[(3 * 12 + nt) * 64 + lane], acc12[nt], 0, 0, 0);
    }

    // biases / head weights (tiny, L2-hot)
    float bz4[4], br4[4], bh4[4], wh4[4];
#pragma unroll
    for (int nt = 0; nt < 4; nt++) {
        bz4[nt] = bias_g[nt * 16 + l15];
        br4[nt] = bias_g[64 + nt * 16 + l15];
        bh4[nt] = bias_g[128 + nt * 16 + l15];
        wh4[nt] = Whead[nt * 16 + l15];
    }
    float bhv = bhead[0];

    // h at C-layout positions (f32, L1-hot rows)
    float hv[4][4];
#pragma unroll
    for (int nt = 0; nt < 4; nt++)
#pragma unroll
        for (int r = 0; r < 4; r++)
            hv[nt][r] = hglob[(size_t)(mb + quad * 4 + r) * 64 + nt * 16 + l15];

    // ---- phase 4: Z, R; hr -> LDS (reuse strip; agg already consumed) ----
    float Z[4][4];
#pragma unroll
    for (int nt = 0; nt < 4; nt++)
#pragma unroll
        for (int r = 0; r < 4; r++) {
            Z[nt][r] = sigm(acc12[nt][r] + bz4[nt]);
            float R = sigm(acc12[4 + nt][r] + br4[nt]);
            myb[(quad * 4 + r) * 72 + nt * 16 + l15] = (__half)(hv[nt][r] * R);
        }
    __builtin_amdgcn_s_waitcnt(0);

    half8 a2f0 = *(const half8*)(myb + l15 * 72 + quad * 8);
    half8 a2f1 = *(const half8*)(myb + l15 * 72 + 32 + quad * 8);

    // ---- phase 5: GEMM2 hr @ B2[64 x 64] accumulated into t-gate ----
#pragma unroll
    for (int nt = 0; nt < 4; nt++) {
        acc12[8 + nt] = __builtin_amdgcn_mfma_f32_16x16x32_f16(a2f0, B2v[(0 * 4 + nt) * 64 + lane], acc12[8 + nt], 0, 0, 0);
        acc12[8 + nt] = __builtin_amdgcn_mfma_f32_16x16x32_f16(a2f1, B2v[(1 * 4 + nt) * 64 + lane], acc12[8 + nt], 0, 0, 0);
    }

    // ---- phase 6: epilogue ----
    float pr0 = 0.f, pr1 = 0.f, pr2 = 0.f, pr3 = 0.f;
#pragma unroll
    for (int nt = 0; nt < 4; nt++) {
#pragma unroll
        for (int r = 0; r < 4; r++) {
            float Ht = tanhfast(acc12[8 + nt][r] + bh4[nt]);
            float z = Z[nt][r];
            float hn = z * hv[nt][r] + (1.f - z) * Ht;
            out_h[(size_t)(mb + quad * 4 + r) * 64 + nt * 16 + l15] = hn;
            float rv = fmaxf(hn, 0.f) * wh4[nt];
            if (r == 0) pr0 += rv; else if (r == 1) pr1 += rv; else if (r == 2) pr2 += rv; else pr3 += rv;
        }
    }
#pragma unroll
    for (int o = 1; o < 16; o <<= 1) {
        pr0 += __shfl_xor(pr0, o);
        pr1 += __shfl_xor(pr1, o);
        pr2 += __shfl_xor(pr2, o);
        pr3 += __shfl_xor(pr3, o);
    }
    if (l15 == 0) {
        out_head[mb + quad * 4 + 0] = pr0 + bhv;
        out_head[mb + quad * 4 + 1] = pr1 + bhv;
        out_head[mb + quad * 4 + 2] = pr2 + bhv;
        out_head[mb + quad * 4 + 3] = pr3 + bhv;
    }
}

extern "C" void kernel_launch(void* const* d_in, const int* in_sizes, int n_in,
                              void* d_out, int out_size, void* d_ws, size_t ws_size,
                              hipStream_t stream) {
    const float* x     = (const float*)d_in[0];
    const int*   src   = (const int*)d_in[1];
    const int*   dst   = (const int*)d_in[2];
    const float* ew    = (const float*)d_in[3];
    const float* h     = (const float*)d_in[4];
    const float* Wcz   = (const float*)d_in[5];
    const float* bcz   = (const float*)d_in[6];
    const float* Wcr   = (const float*)d_in[7];
    const float* bcr   = (const float*)d_in[8];
    const float* Wch   = (const float*)d_in[9];
    const float* bch   = (const float*)d_in[10];
    const float* Wlz   = (const float*)d_in[11];
    const float* blz   = (const float*)d_in[12];
    const float* Wlr   = (const float*)d_in[13];
    const float* blr   = (const float*)d_in[14];
    const float* Wlh   = (const float*)d_in[15];
    const float* blh   = (const float*)d_in[16];
    const float* Whead = (const float*)d_in[17];
    const float* bhead = (const float*)d_in[18];

    int E = in_sizes[1];
    int n = in_sizes[4] / 64;                 // 100000 nodes
    int R = (n + 255) >> 8;                   // 391 buckets of 256 nodes

    // workspace layout
    __half* xs   = (__half*)d_ws;                        // n*64 fp16 (dinv-scaled x)
    u64*   binned = (u64*)(xs + (size_t)n * 64);         // R*CAPC u64
    float* dinv  = (float*)(binned + (size_t)R * CAPC);  // n f32
    int*   off_g = (int*)(dinv + n);                     // n
    int*   len_g = off_g + n;                            // n
    int*   cursor = len_g + n;                           // 1024
    __half* B1f  = (__half*)(cursor + 1024);             // 24576 fp16
    __half* B2f  = B1f + 24576;                          // 4096 fp16
    float* bias  = (float*)(B2f + 4096);                 // 192 f32

    float* out_head = (float*)d_out;          // [n]
    float* out_h    = out_head + n;           // [n*64]

    int nbB = (E + EPB - 1) / EPB;

    k_pre<<<113, 256, 0, stream>>>(Wcz, bcz, Wcr, bcr, Wch, bch,
                                   Wlz, blz, Wlr, blr, Wlh, blh, B1f, B2f, bias, cursor);
    k_bin<<<nbB, 1024, 0, stream>>>(src, dst, ew, cursor, binned, E, R);
    k_sort<<<R, 1024, 0, stream>>>(cursor, binned, (const float2*)x, dinv,
                                   (__half2*)xs, off_g, len_g, n);
    k_gnode<<<(n + 63) / 64, 256, 0, stream>>>(off_g, len_g, binned, dinv, xs, h,
                                               B1f, B2f, bias, Whead, bhead,
                                               out_head, out_h, n);
}